// Round 13
// baseline (780.597 us; speedup 1.0000x reference)
//
#include <hip/hip_runtime.h>

typedef float f32x4 __attribute__((ext_vector_type(4)));

#define T_STEPS 512
#define BATCH   64
#define NIN     512
#define H       1024
#define BH      (BATCH * H)   // 65536

#define BM 128
#define BN 128
#define BK 16
#define LDSS 132

// ---------------------------------------------------------------------------
// Kernel 1: transpose w_rec [j][h] -> wrecT [h][j]  (4 MB, one-time per call)
// ---------------------------------------------------------------------------
__global__ void transpose1024(const float* __restrict__ in, float* __restrict__ out) {
    __shared__ float tile[32][33];
    const int tx = threadIdx.x, ty = threadIdx.y;
    const int xg = blockIdx.x * 32 + tx;
    const int ybase = blockIdx.y * 32;
#pragma unroll
    for (int r = 0; r < 32; r += 8)
        tile[ty + r][tx] = in[(size_t)(ybase + ty + r) * H + xg];
    __syncthreads();
    const int x2 = blockIdx.y * 32 + tx;
    const int y2base = blockIdx.x * 32;
#pragma unroll
    for (int r = 0; r < 32; r += 8)
        out[(size_t)(y2base + ty + r) * H + x2] = tile[tx][ty + r];
}

// ---------------------------------------------------------------------------
// Kernel 2 (R22): cur = x @ w_in^T with REGISTER DOUBLE-BUFFERED K-loop
// (R19's proven pattern, serial form): next K-tile's loads issue before the
// FMA block so load latency hides under compute. FMA order identical to R7.
// ---------------------------------------------------------------------------
__global__ __launch_bounds__(256) void gemm_xwin(const float* __restrict__ x,
                                                 const float* __restrict__ w,
                                                 float* __restrict__ cur) {
    __shared__ __align__(16) float As[BK][LDSS];
    __shared__ __align__(16) float Bs[BK][LDSS];
    const int tid = threadIdx.x;
    const int tx = tid & 15, ty = tid >> 4;
    const int tx4 = tx * 4, ty4 = ty * 4;
    const int m0 = blockIdx.y * BM;
    const int n0 = blockIdx.x * BN;

    float acc[8][8];
#pragma unroll
    for (int i = 0; i < 8; ++i)
#pragma unroll
        for (int j = 0; j < 8; ++j) acc[i][j] = 0.0f;

    const int ar = tid >> 2;
    const int akc = (tid & 3) * 4;

    // prologue: issue k0=0 loads
    float4 a0 = *reinterpret_cast<const float4*>(&x[(size_t)(m0 + ar) * NIN + akc]);
    float4 a1 = *reinterpret_cast<const float4*>(&x[(size_t)(m0 + ar + 64) * NIN + akc]);
    float4 b0 = *reinterpret_cast<const float4*>(&w[(size_t)(n0 + ar) * NIN + akc]);
    float4 b1 = *reinterpret_cast<const float4*>(&w[(size_t)(n0 + ar + 64) * NIN + akc]);

    for (int k0 = 0; k0 < NIN; k0 += BK) {
        __syncthreads();      // prior compute done reading LDS
        As[akc + 0][ar] = a0.x; As[akc + 1][ar] = a0.y; As[akc + 2][ar] = a0.z; As[akc + 3][ar] = a0.w;
        As[akc + 0][ar + 64] = a1.x; As[akc + 1][ar + 64] = a1.y; As[akc + 2][ar + 64] = a1.z; As[akc + 3][ar + 64] = a1.w;
        Bs[akc + 0][ar] = b0.x; Bs[akc + 1][ar] = b0.y; Bs[akc + 2][ar] = b0.z; Bs[akc + 3][ar] = b0.w;
        Bs[akc + 0][ar + 64] = b1.x; Bs[akc + 1][ar + 64] = b1.y; Bs[akc + 2][ar + 64] = b1.z; Bs[akc + 3][ar + 64] = b1.w;
        __syncthreads();

        // issue NEXT K-tile's loads before compute; clamp to 0 on last iter
        // (uniform, branch-free, warm re-read — values unused).
        const int kn = (k0 + BK < NIN) ? (k0 + BK) : 0;
        a0 = *reinterpret_cast<const float4*>(&x[(size_t)(m0 + ar) * NIN + kn + akc]);
        a1 = *reinterpret_cast<const float4*>(&x[(size_t)(m0 + ar + 64) * NIN + kn + akc]);
        b0 = *reinterpret_cast<const float4*>(&w[(size_t)(n0 + ar) * NIN + kn + akc]);
        b1 = *reinterpret_cast<const float4*>(&w[(size_t)(n0 + ar + 64) * NIN + kn + akc]);

#pragma unroll
        for (int kk = 0; kk < BK; ++kk) {
            const float4 av0 = *reinterpret_cast<const float4*>(&As[kk][ty4]);
            const float4 av1 = *reinterpret_cast<const float4*>(&As[kk][ty4 + 64]);
            const float4 bv0 = *reinterpret_cast<const float4*>(&Bs[kk][tx4]);
            const float4 bv1 = *reinterpret_cast<const float4*>(&Bs[kk][tx4 + 64]);
            const float ar_[8] = {av0.x, av0.y, av0.z, av0.w, av1.x, av1.y, av1.z, av1.w};
            const float br_[8] = {bv0.x, bv0.y, bv0.z, bv0.w, bv1.x, bv1.y, bv1.z, bv1.w};
#pragma unroll
            for (int i = 0; i < 8; ++i)
#pragma unroll
                for (int j = 0; j < 8; ++j)
                    acc[i][j] = fmaf(ar_[i], br_[j], acc[i][j]);
        }
    }

#pragma unroll
    for (int gi = 0; gi < 2; ++gi)
#pragma unroll
        for (int ii = 0; ii < 4; ++ii) {
            const int i = gi * 4 + ii;
            const int row = m0 + ty4 + ii + gi * 64;
            float* dst = &cur[(size_t)row * H + n0 + tx4];
            *reinterpret_cast<float4*>(dst)      = make_float4(acc[i][0], acc[i][1], acc[i][2], acc[i][3]);
            *reinterpret_cast<float4*>(dst + 64) = make_float4(acc[i][4], acc[i][5], acc[i][6], acc[i][7]);
        }
}

// ---------------------------------------------------------------------------
// Kernel 3 (R22): async-LDS ring-pipelined gather scan, 8-ROW GROUPS.
//   R21 structure (proven: 452 -> ~340 us) with ring slots widened 4 -> 8
//   rows: ring[3][8][1024] = 96 KB (1 block/CU — scan uses only 64 CUs),
//   NT = ceil(n/8) ~ 4.4 groups/step -> half the vmcnt wait boundaries.
//   Counted waits become vmcnt(16/8/0). All other structure, accumulation
//   order (flat ascending list = R8 order), clamped rows + fmaf-masked tail
//   are R21-verbatim (absmax 0.0).
// ---------------------------------------------------------------------------
__global__ __launch_bounds__(256, 1) void lsnn_scan_kernel(float* __restrict__ io,
                                                           const float* __restrict__ wrecT) {
    const int tid = threadIdx.x;
    const int wave = tid >> 6, lane = tid & 63;
    const int j0 = tid * 4;
    const int wq = wave * 256;          // this wave's column quarter (floats)
    const int b = blockIdx.x;

    __shared__ __align__(16) float ring[3][8][1024];   // 96 KB gather ring
    __shared__ __align__(16) int list[2][1088];        // merged spike list
    __shared__ __align__(16) int cnt[2][4];

    float sv0 = 0.f, sv1 = 0.f, sv2 = 0.f, sv3 = 0.f;
    float si0 = 0.f, si1 = 0.f, si2 = 0.f, si3 = 0.f;
    float sb0 = 1.f, sb1 = 1.f, sb2 = 1.f, sb3 = 1.f;
    float sz0 = 0.f, sz1 = 0.f, sz2 = 0.f, sz3 = 0.f;
    int p = 0;
    int n_carry = 0;

    const float C_MEM = (float)(1e-3 * 100.0);
    const float C_SYN = (float)(1e-3 * 200.0);
    const float C_AD  = (float)(1e-3 * (1.0 / 800.0));
    const float BETA  = 1.8f;

    float* base = io + (size_t)b * H + j0;

    // chunk prefetch buffers: 8 steps of cur (plain loads; GEMM ran before us)
    f32x4 P0 = *reinterpret_cast<const f32x4*>(base + (size_t)0 * BH);
    f32x4 P1 = *reinterpret_cast<const f32x4*>(base + (size_t)1 * BH);
    f32x4 P2 = *reinterpret_cast<const f32x4*>(base + (size_t)2 * BH);
    f32x4 P3 = *reinterpret_cast<const f32x4*>(base + (size_t)3 * BH);
    f32x4 P4 = *reinterpret_cast<const f32x4*>(base + (size_t)4 * BH);
    f32x4 P5 = *reinterpret_cast<const f32x4*>(base + (size_t)5 * BH);
    f32x4 P6 = *reinterpret_cast<const f32x4*>(base + (size_t)6 * BH);
    f32x4 P7 = *reinterpret_cast<const f32x4*>(base + (size_t)7 * BH);

// stage group G (8 rows) into ring slot SLOT: per wave, 8 global_load_lds of
// this wave's 1KB row-quarter. Row index clamped to 0 for positions >= n
// (always-issued, safe, L2-hot; masked at accumulate — exact).
#define STAGE(G, SLOT)                                                        \
  { const int A0s_ = (G) << 3;                                                \
    _Pragma("unroll")                                                         \
    for (int rr_ = 0; rr_ < 8; ++rr_) {                                       \
      const int ps_ = A0s_ + rr_;                                             \
      int hs_ = lst[ps_];                                                     \
      hs_ = (ps_ < n) ? hs_ : 0;                                              \
      const float* gp_ = wrecT + (size_t)(unsigned)hs_ * H + wq + lane * 4;   \
      __builtin_amdgcn_global_load_lds(                                       \
          (const __attribute__((address_space(1))) unsigned int*)gp_,         \
          (__attribute__((address_space(3))) unsigned int*)&ring[SLOT][rr_][wq], \
          16, 0, 0);                                                          \
    } }

#define ACCROW(WREG) { r0 += WREG.x; r1 += WREG.y; r2 += WREG.z; r3 += WREG.w; }
#define ACCROWM(WREG, POS)                                                    \
  { const float mm_ = ((POS) < n) ? 1.0f : 0.0f;                              \
    r0 = fmaf(mm_, WREG.x, r0); r1 = fmaf(mm_, WREG.y, r1);                   \
    r2 = fmaf(mm_, WREG.z, r2); r3 = fmaf(mm_, WREG.w, r3); }

#define SCAN_STEP(T, CREG, PF)                                                \
  {                                                                           \
    const float cc0 = CREG.x, cc1 = CREG.y, cc2 = CREG.z, cc3 = CREG.w;       \
    const int n = __builtin_amdgcn_readfirstlane(n_carry);                    \
    const int NT = (n + 7) >> 3;                                              \
    const int* lst = &list[p][0];                                             \
    /* issue first three groups NOW; latency hides under dynamics+barriers */ \
    if (NT > 0) STAGE(0, 0);                                                  \
    if (NT > 1) STAGE(1, 1);                                                  \
    if (NT > 2) STAGE(2, 2);                                                  \
    /* dynamics (bit-identical ops, R8 order) */                              \
    const float vd0 = sv0 + C_MEM * (0.0f - sv0 + si0);                       \
    const float vd1 = sv1 + C_MEM * (0.0f - sv1 + si1);                       \
    const float vd2 = sv2 + C_MEM * (0.0f - sv2 + si2);                       \
    const float vd3 = sv3 + C_MEM * (0.0f - sv3 + si3);                       \
    const float id0 = si0 - C_SYN * si0;                                      \
    const float id1 = si1 - C_SYN * si1;                                      \
    const float id2 = si2 - C_SYN * si2;                                      \
    const float id3 = si3 - C_SYN * si3;                                      \
    const float bd0 = sb0 + C_AD * (1.0f - sb0);                              \
    const float bd1 = sb1 + C_AD * (1.0f - sb1);                              \
    const float bd2 = sb2 + C_AD * (1.0f - sb2);                              \
    const float bd3 = sb3 + C_AD * (1.0f - sb3);                              \
    sz0 = ((vd0 - bd0) > 0.0f) ? 1.0f : 0.0f;                                 \
    sz1 = ((vd1 - bd1) > 0.0f) ? 1.0f : 0.0f;                                 \
    sz2 = ((vd2 - bd2) > 0.0f) ? 1.0f : 0.0f;                                 \
    sz3 = ((vd3 - bd3) > 0.0f) ? 1.0f : 0.0f;                                 \
    sv0 = (sz0 > 0.0f) ? 0.0f : vd0;                                          \
    sv1 = (sz1 > 0.0f) ? 0.0f : vd1;                                          \
    sv2 = (sz2 > 0.0f) ? 0.0f : vd2;                                          \
    sv3 = (sz3 > 0.0f) ? 0.0f : vd3;                                          \
    sb0 = (sz0 > 0.0f) ? (bd0 + BETA) : bd0;                                  \
    sb1 = (sz1 > 0.0f) ? (bd1 + BETA) : bd1;                                  \
    sb2 = (sz2 > 0.0f) ? (bd2 + BETA) : bd2;                                  \
    sb3 = (sz3 > 0.0f) ? (bd3 + BETA) : bd3;                                  \
    *reinterpret_cast<f32x4*>(base + (size_t)(T) * BH) =                      \
        (f32x4){sz0, sz1, sz2, sz3};                                          \
    const unsigned long long m0 = __ballot(sz0 > 0.0f);                       \
    const unsigned long long m1 = __ballot(sz1 > 0.0f);                       \
    const unsigned long long m2 = __ballot(sz2 > 0.0f);                       \
    const unsigned long long m3 = __ballot(sz3 > 0.0f);                       \
    unsigned pos = __builtin_amdgcn_mbcnt_hi((unsigned)(m0 >> 32),            \
                   __builtin_amdgcn_mbcnt_lo((unsigned)m0, 0u));              \
    pos = __builtin_amdgcn_mbcnt_hi((unsigned)(m1 >> 32),                     \
          __builtin_amdgcn_mbcnt_lo((unsigned)m1, pos));                      \
    pos = __builtin_amdgcn_mbcnt_hi((unsigned)(m2 >> 32),                     \
          __builtin_amdgcn_mbcnt_lo((unsigned)m2, pos));                      \
    pos = __builtin_amdgcn_mbcnt_hi((unsigned)(m3 >> 32),                     \
          __builtin_amdgcn_mbcnt_lo((unsigned)m3, pos));                      \
    if (lane == 0)                                                            \
      cnt[p ^ 1][wave] = __popcll(m0) + __popcll(m1) + __popcll(m2) + __popcll(m3); \
    asm volatile("s_waitcnt lgkmcnt(0)" ::: "memory");                        \
    __builtin_amdgcn_s_barrier();                                             \
    const int4 nc = *reinterpret_cast<const int4*>(&cnt[p ^ 1][0]);           \
    n_carry = nc.x + nc.y + nc.z + nc.w;                                      \
    const int woff = (wave > 0 ? nc.x : 0) + (wave > 1 ? nc.y : 0) +          \
                     (wave > 2 ? nc.z : 0);                                   \
    int* dst = &list[p ^ 1][woff];                                            \
    if (sz0 > 0.0f) dst[pos++] = j0 + 0;                                      \
    if (sz1 > 0.0f) dst[pos++] = j0 + 1;                                      \
    if (sz2 > 0.0f) dst[pos++] = j0 + 2;                                      \
    if (sz3 > 0.0f) dst[pos++] = j0 + 3;                                      \
    asm volatile("s_waitcnt lgkmcnt(0)" ::: "memory");                        \
    __builtin_amdgcn_s_barrier();                                             \
    /* ring-pipelined gather: read g while g+1,g+2 in flight; stage g+3 */    \
    float r0 = 0.f, r1 = 0.f, r2 = 0.f, r3 = 0.f;                             \
    {                                                                         \
      int sl = 0;                                                             \
      for (int g = 0; g < NT; ++g) {                                          \
        const int rem = NT - 1 - g;                                           \
        if (rem >= 2)      { asm volatile("s_waitcnt vmcnt(16)" ::: "memory"); } \
        else if (rem == 1) { asm volatile("s_waitcnt vmcnt(8)" ::: "memory"); } \
        else               { asm volatile("s_waitcnt vmcnt(0)" ::: "memory"); } \
        const f32x4 w0 = *reinterpret_cast<const f32x4*>(&ring[sl][0][j0]);   \
        const f32x4 w1 = *reinterpret_cast<const f32x4*>(&ring[sl][1][j0]);   \
        const f32x4 w2 = *reinterpret_cast<const f32x4*>(&ring[sl][2][j0]);   \
        const f32x4 w3 = *reinterpret_cast<const f32x4*>(&ring[sl][3][j0]);   \
        const f32x4 w4 = *reinterpret_cast<const f32x4*>(&ring[sl][4][j0]);   \
        const f32x4 w5 = *reinterpret_cast<const f32x4*>(&ring[sl][5][j0]);   \
        const f32x4 w6 = *reinterpret_cast<const f32x4*>(&ring[sl][6][j0]);   \
        const f32x4 w7 = *reinterpret_cast<const f32x4*>(&ring[sl][7][j0]);   \
        const int gb = g << 3;                                                \
        if (gb + 8 <= n) {                                                    \
          ACCROW(w0) ACCROW(w1) ACCROW(w2) ACCROW(w3)                         \
          ACCROW(w4) ACCROW(w5) ACCROW(w6) ACCROW(w7)                         \
        } else {                                                              \
          ACCROWM(w0, gb + 0) ACCROWM(w1, gb + 1)                             \
          ACCROWM(w2, gb + 2) ACCROWM(w3, gb + 3)                             \
          ACCROWM(w4, gb + 4) ACCROWM(w5, gb + 5)                             \
          ACCROWM(w6, gb + 6) ACCROWM(w7, gb + 7)                             \
        }                                                                     \
        if (g + 3 < NT) {                                                     \
          /* slot sl fully consumed (adds forced lgkm waits); reuse it */     \
          asm volatile("s_waitcnt lgkmcnt(0)" ::: "memory");                  \
          STAGE(g + 3, sl);                                                   \
        }                                                                     \
        sl = (sl == 2) ? 0 : sl + 1;                                          \
      }                                                                       \
    }                                                                         \
    if (PF) {                                                                 \
      if ((T) + 1 < T_STEPS) {                                                \
        const float* pb = base + (size_t)((T) + 1) * BH;                      \
        P0 = *(const f32x4*)(pb + (size_t)0 * BH);                            \
        P1 = *(const f32x4*)(pb + (size_t)1 * BH);                            \
        P2 = *(const f32x4*)(pb + (size_t)2 * BH);                            \
        P3 = *(const f32x4*)(pb + (size_t)3 * BH);                            \
        P4 = *(const f32x4*)(pb + (size_t)4 * BH);                            \
        P5 = *(const f32x4*)(pb + (size_t)5 * BH);                            \
        P6 = *(const f32x4*)(pb + (size_t)6 * BH);                            \
        P7 = *(const f32x4*)(pb + (size_t)7 * BH);                            \
      }                                                                       \
    }                                                                         \
    si0 = (id0 + cc0) + r0;                                                   \
    si1 = (id1 + cc1) + r1;                                                   \
    si2 = (id2 + cc2) + r2;                                                   \
    si3 = (id3 + cc3) + r3;                                                   \
    p ^= 1;                                                                   \
  }

    for (int t = 0; t < T_STEPS; t += 8) {
        SCAN_STEP(t,     P0, 0);
        SCAN_STEP(t + 1, P1, 0);
        SCAN_STEP(t + 2, P2, 0);
        SCAN_STEP(t + 3, P3, 0);
        SCAN_STEP(t + 4, P4, 0);
        SCAN_STEP(t + 5, P5, 0);
        SCAN_STEP(t + 6, P6, 0);
        SCAN_STEP(t + 7, P7, 1);
    }
#undef SCAN_STEP
#undef ACCROWM
#undef ACCROW
#undef STAGE

    float* fo = io + (size_t)T_STEPS * BH + (size_t)b * H + j0;
    *reinterpret_cast<float4*>(fo)          = make_float4(sz0, sz1, sz2, sz3);
    *reinterpret_cast<float4*>(fo + BH)     = make_float4(sv0, sv1, sv2, sv3);
    *reinterpret_cast<float4*>(fo + 2 * BH) = make_float4(si0, si1, si2, si3);
    *reinterpret_cast<float4*>(fo + 3 * BH) = make_float4(sb0, sb1, sb2, sb3);
}

// ---------------------------------------------------------------------------
extern "C" void kernel_launch(void* const* d_in, const int* in_sizes, int n_in,
                              void* d_out, int out_size, void* d_ws, size_t ws_size,
                              hipStream_t stream) {
    const float* x     = (const float*)d_in[0];
    const float* w_in  = (const float*)d_in[1];
    const float* w_rec = (const float*)d_in[2];
    float* out   = (float*)d_out;
    float* wrecT = (float*)d_ws;

    transpose1024<<<dim3(H / 32, H / 32), dim3(32, 8), 0, stream>>>(w_rec, wrecT);
    gemm_xwin<<<dim3(H / BN, (T_STEPS * BATCH) / BM), 256, 0, stream>>>(x, w_in, out);
    lsnn_scan_kernel<<<BATCH, 256, 0, stream>>>(out, wrecT);
}

// Round 14
// 747.933 us; speedup vs baseline: 1.0437x; 1.0437x over previous
//
#include <hip/hip_runtime.h>

typedef float f32x4 __attribute__((ext_vector_type(4)));

#define T_STEPS 512
#define BATCH   64
#define NIN     512
#define H       1024
#define BH      (BATCH * H)   // 65536

#define BM 128
#define BN 128
#define BK 16
#define LDSS 132

// ---------------------------------------------------------------------------
// Kernel 1: transpose w_rec [j][h] -> wrecT [h][j]  (4 MB, one-time per call)
// ---------------------------------------------------------------------------
__global__ void transpose1024(const float* __restrict__ in, float* __restrict__ out) {
    __shared__ float tile[32][33];
    const int tx = threadIdx.x, ty = threadIdx.y;
    const int xg = blockIdx.x * 32 + tx;
    const int ybase = blockIdx.y * 32;
#pragma unroll
    for (int r = 0; r < 32; r += 8)
        tile[ty + r][tx] = in[(size_t)(ybase + ty + r) * H + xg];
    __syncthreads();
    const int x2 = blockIdx.y * 32 + tx;
    const int y2base = blockIdx.x * 32;
#pragma unroll
    for (int r = 0; r < 32; r += 8)
        out[(size_t)(y2base + ty + r) * H + x2] = tile[tx][ty + r];
}

// ---------------------------------------------------------------------------
// Kernel 2 (R22-proven): cur = x @ w_in^T, register double-buffered K-loop
// (next K-tile's loads issue before the FMA block). FMA order identical to
// R7. Measured ~366 us (vs 408 non-dbuf).
// ---------------------------------------------------------------------------
__global__ __launch_bounds__(256) void gemm_xwin(const float* __restrict__ x,
                                                 const float* __restrict__ w,
                                                 float* __restrict__ cur) {
    __shared__ __align__(16) float As[BK][LDSS];
    __shared__ __align__(16) float Bs[BK][LDSS];
    const int tid = threadIdx.x;
    const int tx = tid & 15, ty = tid >> 4;
    const int tx4 = tx * 4, ty4 = ty * 4;
    const int m0 = blockIdx.y * BM;
    const int n0 = blockIdx.x * BN;

    float acc[8][8];
#pragma unroll
    for (int i = 0; i < 8; ++i)
#pragma unroll
        for (int j = 0; j < 8; ++j) acc[i][j] = 0.0f;

    const int ar = tid >> 2;
    const int akc = (tid & 3) * 4;

    // prologue: issue k0=0 loads
    float4 a0 = *reinterpret_cast<const float4*>(&x[(size_t)(m0 + ar) * NIN + akc]);
    float4 a1 = *reinterpret_cast<const float4*>(&x[(size_t)(m0 + ar + 64) * NIN + akc]);
    float4 b0 = *reinterpret_cast<const float4*>(&w[(size_t)(n0 + ar) * NIN + akc]);
    float4 b1 = *reinterpret_cast<const float4*>(&w[(size_t)(n0 + ar + 64) * NIN + akc]);

    for (int k0 = 0; k0 < NIN; k0 += BK) {
        __syncthreads();      // prior compute done reading LDS
        As[akc + 0][ar] = a0.x; As[akc + 1][ar] = a0.y; As[akc + 2][ar] = a0.z; As[akc + 3][ar] = a0.w;
        As[akc + 0][ar + 64] = a1.x; As[akc + 1][ar + 64] = a1.y; As[akc + 2][ar + 64] = a1.z; As[akc + 3][ar + 64] = a1.w;
        Bs[akc + 0][ar] = b0.x; Bs[akc + 1][ar] = b0.y; Bs[akc + 2][ar] = b0.z; Bs[akc + 3][ar] = b0.w;
        Bs[akc + 0][ar + 64] = b1.x; Bs[akc + 1][ar + 64] = b1.y; Bs[akc + 2][ar + 64] = b1.z; Bs[akc + 3][ar + 64] = b1.w;
        __syncthreads();

        // issue NEXT K-tile's loads before compute; clamp to 0 on last iter
        // (uniform, branch-free, warm re-read — values unused).
        const int kn = (k0 + BK < NIN) ? (k0 + BK) : 0;
        a0 = *reinterpret_cast<const float4*>(&x[(size_t)(m0 + ar) * NIN + kn + akc]);
        a1 = *reinterpret_cast<const float4*>(&x[(size_t)(m0 + ar + 64) * NIN + kn + akc]);
        b0 = *reinterpret_cast<const float4*>(&w[(size_t)(n0 + ar) * NIN + kn + akc]);
        b1 = *reinterpret_cast<const float4*>(&w[(size_t)(n0 + ar + 64) * NIN + kn + akc]);

#pragma unroll
        for (int kk = 0; kk < BK; ++kk) {
            const float4 av0 = *reinterpret_cast<const float4*>(&As[kk][ty4]);
            const float4 av1 = *reinterpret_cast<const float4*>(&As[kk][ty4 + 64]);
            const float4 bv0 = *reinterpret_cast<const float4*>(&Bs[kk][tx4]);
            const float4 bv1 = *reinterpret_cast<const float4*>(&Bs[kk][tx4 + 64]);
            const float ar_[8] = {av0.x, av0.y, av0.z, av0.w, av1.x, av1.y, av1.z, av1.w};
            const float br_[8] = {bv0.x, bv0.y, bv0.z, bv0.w, bv1.x, bv1.y, bv1.z, bv1.w};
#pragma unroll
            for (int i = 0; i < 8; ++i)
#pragma unroll
                for (int j = 0; j < 8; ++j)
                    acc[i][j] = fmaf(ar_[i], br_[j], acc[i][j]);
        }
    }

#pragma unroll
    for (int gi = 0; gi < 2; ++gi)
#pragma unroll
        for (int ii = 0; ii < 4; ++ii) {
            const int i = gi * 4 + ii;
            const int row = m0 + ty4 + ii + gi * 64;
            float* dst = &cur[(size_t)row * H + n0 + tx4];
            *reinterpret_cast<float4*>(dst)      = make_float4(acc[i][0], acc[i][1], acc[i][2], acc[i][3]);
            *reinterpret_cast<float4*>(dst + 64) = make_float4(acc[i][4], acc[i][5], acc[i][6], acc[i][7]);
        }
}

// ---------------------------------------------------------------------------
// Kernel 3 (R21-proven, verbatim): async-LDS ring-pipelined gather scan,
// 4-ROW GROUPS. ring[3][4][1024] = 48 KB; counted waits vmcnt(8/4/0);
// groups 0..2 issue at step top (latency hides under dynamics + ballot +
// 2 raw barriers); merged flat spike list; clamped rows + fmaf-masked tail.
// Accumulation order = flat ascending list = R8 order (absmax 0.0).
// Measured ~340 us (vs R8's 452; R22's 8-row widening regressed to 406 —
// pipeline depth amortizes latency, group width does not).
// ---------------------------------------------------------------------------
__global__ __launch_bounds__(256, 1) void lsnn_scan_kernel(float* __restrict__ io,
                                                           const float* __restrict__ wrecT) {
    const int tid = threadIdx.x;
    const int wave = tid >> 6, lane = tid & 63;
    const int j0 = tid * 4;
    const int wq = wave * 256;          // this wave's column quarter (floats)
    const int b = blockIdx.x;

    __shared__ __align__(16) float ring[3][4][1024];   // 48 KB gather ring
    __shared__ __align__(16) int list[2][1088];        // merged spike list
    __shared__ __align__(16) int cnt[2][4];

    float sv0 = 0.f, sv1 = 0.f, sv2 = 0.f, sv3 = 0.f;
    float si0 = 0.f, si1 = 0.f, si2 = 0.f, si3 = 0.f;
    float sb0 = 1.f, sb1 = 1.f, sb2 = 1.f, sb3 = 1.f;
    float sz0 = 0.f, sz1 = 0.f, sz2 = 0.f, sz3 = 0.f;
    int p = 0;
    int n_carry = 0;

    const float C_MEM = (float)(1e-3 * 100.0);
    const float C_SYN = (float)(1e-3 * 200.0);
    const float C_AD  = (float)(1e-3 * (1.0 / 800.0));
    const float BETA  = 1.8f;

    float* base = io + (size_t)b * H + j0;

    // chunk prefetch buffers: 8 steps of cur (plain loads; GEMM ran before us)
    f32x4 P0 = *reinterpret_cast<const f32x4*>(base + (size_t)0 * BH);
    f32x4 P1 = *reinterpret_cast<const f32x4*>(base + (size_t)1 * BH);
    f32x4 P2 = *reinterpret_cast<const f32x4*>(base + (size_t)2 * BH);
    f32x4 P3 = *reinterpret_cast<const f32x4*>(base + (size_t)3 * BH);
    f32x4 P4 = *reinterpret_cast<const f32x4*>(base + (size_t)4 * BH);
    f32x4 P5 = *reinterpret_cast<const f32x4*>(base + (size_t)5 * BH);
    f32x4 P6 = *reinterpret_cast<const f32x4*>(base + (size_t)6 * BH);
    f32x4 P7 = *reinterpret_cast<const f32x4*>(base + (size_t)7 * BH);

// stage group G (4 rows) into ring slot SLOT: per wave, 4 global_load_lds of
// this wave's 1KB quarter. Row index clamped to 0 for positions >= n
// (always-issued, safe, L2-hot; masked at accumulate — exact).
#define STAGE(G, SLOT)                                                        \
  { const int A0s_ = (G) << 2;                                                \
    _Pragma("unroll")                                                         \
    for (int rr_ = 0; rr_ < 4; ++rr_) {                                       \
      const int ps_ = A0s_ + rr_;                                             \
      int hs_ = lst[ps_];                                                     \
      hs_ = (ps_ < n) ? hs_ : 0;                                              \
      const float* gp_ = wrecT + (size_t)(unsigned)hs_ * H + wq + lane * 4;   \
      __builtin_amdgcn_global_load_lds(                                       \
          (const __attribute__((address_space(1))) unsigned int*)gp_,         \
          (__attribute__((address_space(3))) unsigned int*)&ring[SLOT][rr_][wq], \
          16, 0, 0);                                                          \
    } }

#define SCAN_STEP(T, CREG, PF)                                                \
  {                                                                           \
    const float cc0 = CREG.x, cc1 = CREG.y, cc2 = CREG.z, cc3 = CREG.w;       \
    const int n = __builtin_amdgcn_readfirstlane(n_carry);                    \
    const int NT = (n + 3) >> 2;                                              \
    const int* lst = &list[p][0];                                             \
    /* issue first three groups NOW; latency hides under dynamics+barriers */ \
    if (NT > 0) STAGE(0, 0);                                                  \
    if (NT > 1) STAGE(1, 1);                                                  \
    if (NT > 2) STAGE(2, 2);                                                  \
    /* dynamics (bit-identical ops, R8 order) */                              \
    const float vd0 = sv0 + C_MEM * (0.0f - sv0 + si0);                       \
    const float vd1 = sv1 + C_MEM * (0.0f - sv1 + si1);                       \
    const float vd2 = sv2 + C_MEM * (0.0f - sv2 + si2);                       \
    const float vd3 = sv3 + C_MEM * (0.0f - sv3 + si3);                       \
    const float id0 = si0 - C_SYN * si0;                                      \
    const float id1 = si1 - C_SYN * si1;                                      \
    const float id2 = si2 - C_SYN * si2;                                      \
    const float id3 = si3 - C_SYN * si3;                                      \
    const float bd0 = sb0 + C_AD * (1.0f - sb0);                              \
    const float bd1 = sb1 + C_AD * (1.0f - sb1);                              \
    const float bd2 = sb2 + C_AD * (1.0f - sb2);                              \
    const float bd3 = sb3 + C_AD * (1.0f - sb3);                              \
    sz0 = ((vd0 - bd0) > 0.0f) ? 1.0f : 0.0f;                                 \
    sz1 = ((vd1 - bd1) > 0.0f) ? 1.0f : 0.0f;                                 \
    sz2 = ((vd2 - bd2) > 0.0f) ? 1.0f : 0.0f;                                 \
    sz3 = ((vd3 - bd3) > 0.0f) ? 1.0f : 0.0f;                                 \
    sv0 = (sz0 > 0.0f) ? 0.0f : vd0;                                          \
    sv1 = (sz1 > 0.0f) ? 0.0f : vd1;                                          \
    sv2 = (sz2 > 0.0f) ? 0.0f : vd2;                                          \
    sv3 = (sz3 > 0.0f) ? 0.0f : vd3;                                          \
    sb0 = (sz0 > 0.0f) ? (bd0 + BETA) : bd0;                                  \
    sb1 = (sz1 > 0.0f) ? (bd1 + BETA) : bd1;                                  \
    sb2 = (sz2 > 0.0f) ? (bd2 + BETA) : bd2;                                  \
    sb3 = (sz3 > 0.0f) ? (bd3 + BETA) : bd3;                                  \
    *reinterpret_cast<f32x4*>(base + (size_t)(T) * BH) =                      \
        (f32x4){sz0, sz1, sz2, sz3};                                          \
    const unsigned long long m0 = __ballot(sz0 > 0.0f);                       \
    const unsigned long long m1 = __ballot(sz1 > 0.0f);                       \
    const unsigned long long m2 = __ballot(sz2 > 0.0f);                       \
    const unsigned long long m3 = __ballot(sz3 > 0.0f);                       \
    unsigned pos = __builtin_amdgcn_mbcnt_hi((unsigned)(m0 >> 32),            \
                   __builtin_amdgcn_mbcnt_lo((unsigned)m0, 0u));              \
    pos = __builtin_amdgcn_mbcnt_hi((unsigned)(m1 >> 32),                     \
          __builtin_amdgcn_mbcnt_lo((unsigned)m1, pos));                      \
    pos = __builtin_amdgcn_mbcnt_hi((unsigned)(m2 >> 32),                     \
          __builtin_amdgcn_mbcnt_lo((unsigned)m2, pos));                      \
    pos = __builtin_amdgcn_mbcnt_hi((unsigned)(m3 >> 32),                     \
          __builtin_amdgcn_mbcnt_lo((unsigned)m3, pos));                      \
    if (lane == 0)                                                            \
      cnt[p ^ 1][wave] = __popcll(m0) + __popcll(m1) + __popcll(m2) + __popcll(m3); \
    asm volatile("s_waitcnt lgkmcnt(0)" ::: "memory");                        \
    __builtin_amdgcn_s_barrier();                                             \
    const int4 nc = *reinterpret_cast<const int4*>(&cnt[p ^ 1][0]);           \
    n_carry = nc.x + nc.y + nc.z + nc.w;                                      \
    const int woff = (wave > 0 ? nc.x : 0) + (wave > 1 ? nc.y : 0) +          \
                     (wave > 2 ? nc.z : 0);                                   \
    int* dst = &list[p ^ 1][woff];                                            \
    if (sz0 > 0.0f) dst[pos++] = j0 + 0;                                      \
    if (sz1 > 0.0f) dst[pos++] = j0 + 1;                                      \
    if (sz2 > 0.0f) dst[pos++] = j0 + 2;                                      \
    if (sz3 > 0.0f) dst[pos++] = j0 + 3;                                      \
    asm volatile("s_waitcnt lgkmcnt(0)" ::: "memory");                        \
    __builtin_amdgcn_s_barrier();                                             \
    /* ring-pipelined gather: read g while g+1,g+2 in flight; stage g+3 */    \
    float r0 = 0.f, r1 = 0.f, r2 = 0.f, r3 = 0.f;                             \
    {                                                                         \
      int sl = 0;                                                             \
      for (int g = 0; g < NT; ++g) {                                          \
        const int rem = NT - 1 - g;                                           \
        if (rem >= 2)      { asm volatile("s_waitcnt vmcnt(8)" ::: "memory"); } \
        else if (rem == 1) { asm volatile("s_waitcnt vmcnt(4)" ::: "memory"); } \
        else               { asm volatile("s_waitcnt vmcnt(0)" ::: "memory"); } \
        const f32x4 w0 = *reinterpret_cast<const f32x4*>(&ring[sl][0][j0]);   \
        const f32x4 w1 = *reinterpret_cast<const f32x4*>(&ring[sl][1][j0]);   \
        const f32x4 w2 = *reinterpret_cast<const f32x4*>(&ring[sl][2][j0]);   \
        const f32x4 w3 = *reinterpret_cast<const f32x4*>(&ring[sl][3][j0]);   \
        const int gb = g << 2;                                                \
        if (gb + 4 <= n) {                                                    \
          r0 += w0.x; r1 += w0.y; r2 += w0.z; r3 += w0.w;                     \
          r0 += w1.x; r1 += w1.y; r2 += w1.z; r3 += w1.w;                     \
          r0 += w2.x; r1 += w2.y; r2 += w2.z; r3 += w2.w;                     \
          r0 += w3.x; r1 += w3.y; r2 += w3.z; r3 += w3.w;                     \
        } else {                                                              \
          const float ma_ = (gb + 0 < n) ? 1.0f : 0.0f;                       \
          r0 = fmaf(ma_, w0.x, r0); r1 = fmaf(ma_, w0.y, r1);                 \
          r2 = fmaf(ma_, w0.z, r2); r3 = fmaf(ma_, w0.w, r3);                 \
          const float mb_ = (gb + 1 < n) ? 1.0f : 0.0f;                       \
          r0 = fmaf(mb_, w1.x, r0); r1 = fmaf(mb_, w1.y, r1);                 \
          r2 = fmaf(mb_, w1.z, r2); r3 = fmaf(mb_, w1.w, r3);                 \
          const float mc_ = (gb + 2 < n) ? 1.0f : 0.0f;                       \
          r0 = fmaf(mc_, w2.x, r0); r1 = fmaf(mc_, w2.y, r1);                 \
          r2 = fmaf(mc_, w2.z, r2); r3 = fmaf(mc_, w2.w, r3);                 \
          const float md_ = (gb + 3 < n) ? 1.0f : 0.0f;                       \
          r0 = fmaf(md_, w3.x, r0); r1 = fmaf(md_, w3.y, r1);                 \
          r2 = fmaf(md_, w3.z, r2); r3 = fmaf(md_, w3.w, r3);                 \
        }                                                                     \
        if (g + 3 < NT) {                                                     \
          /* slot sl is fully consumed (adds forced lgkm wait); reuse it */   \
          asm volatile("s_waitcnt lgkmcnt(0)" ::: "memory");                  \
          STAGE(g + 3, sl);                                                   \
        }                                                                     \
        sl = (sl == 2) ? 0 : sl + 1;                                          \
      }                                                                       \
    }                                                                         \
    if (PF) {                                                                 \
      if ((T) + 1 < T_STEPS) {                                                \
        const float* pb = base + (size_t)((T) + 1) * BH;                      \
        P0 = *(const f32x4*)(pb + (size_t)0 * BH);                            \
        P1 = *(const f32x4*)(pb + (size_t)1 * BH);                            \
        P2 = *(const f32x4*)(pb + (size_t)2 * BH);                            \
        P3 = *(const f32x4*)(pb + (size_t)3 * BH);                            \
        P4 = *(const f32x4*)(pb + (size_t)4 * BH);                            \
        P5 = *(const f32x4*)(pb + (size_t)5 * BH);                            \
        P6 = *(const f32x4*)(pb + (size_t)6 * BH);                            \
        P7 = *(const f32x4*)(pb + (size_t)7 * BH);                            \
      }                                                                       \
    }                                                                         \
    si0 = (id0 + cc0) + r0;                                                   \
    si1 = (id1 + cc1) + r1;                                                   \
    si2 = (id2 + cc2) + r2;                                                   \
    si3 = (id3 + cc3) + r3;                                                   \
    p ^= 1;                                                                   \
  }

    for (int t = 0; t < T_STEPS; t += 8) {
        SCAN_STEP(t,     P0, 0);
        SCAN_STEP(t + 1, P1, 0);
        SCAN_STEP(t + 2, P2, 0);
        SCAN_STEP(t + 3, P3, 0);
        SCAN_STEP(t + 4, P4, 0);
        SCAN_STEP(t + 5, P5, 0);
        SCAN_STEP(t + 6, P6, 0);
        SCAN_STEP(t + 7, P7, 1);
    }
#undef SCAN_STEP
#undef STAGE

    float* fo = io + (size_t)T_STEPS * BH + (size_t)b * H + j0;
    *reinterpret_cast<float4*>(fo)          = make_float4(sz0, sz1, sz2, sz3);
    *reinterpret_cast<float4*>(fo + BH)     = make_float4(sv0, sv1, sv2, sv3);
    *reinterpret_cast<float4*>(fo + 2 * BH) = make_float4(si0, si1, si2, si3);
    *reinterpret_cast<float4*>(fo + 3 * BH) = make_float4(sb0, sb1, sb2, sb3);
}

// ---------------------------------------------------------------------------
extern "C" void kernel_launch(void* const* d_in, const int* in_sizes, int n_in,
                              void* d_out, int out_size, void* d_ws, size_t ws_size,
                              hipStream_t stream) {
    const float* x     = (const float*)d_in[0];
    const float* w_in  = (const float*)d_in[1];
    const float* w_rec = (const float*)d_in[2];
    float* out   = (float*)d_out;
    float* wrecT = (float*)d_ws;

    transpose1024<<<dim3(H / 32, H / 32), dim3(32, 8), 0, stream>>>(w_rec, wrecT);
    gemm_xwin<<<dim3(H / BN, (T_STEPS * BATCH) / BM), 256, 0, stream>>>(x, w_in, out);
    lsnn_scan_kernel<<<BATCH, 256, 0, stream>>>(out, wrecT);
}